// Round 5
// baseline (397.799 us; speedup 1.0000x reference)
//
#include <hip/hip_runtime.h>

// Problem constants
#define SEQ   2048
#define BATCH 16
#define CINCH 512
#define HDIM  512
#define NDIM  1536            // 3*H
#define TBM   (SEQ*BATCH)     // 32768 = GEMM M
#define KRED  1024            // Cin*K = GEMM K
#define NCH   32              // scan chunks
#define CHL   64              // chunk length (NCH*CHL == SEQ)
#define NCOL  8192            // B*H chains

typedef unsigned short ushort_t;
typedef __bf16 bf16x8 __attribute__((ext_vector_type(8)));
typedef unsigned short u16x8 __attribute__((ext_vector_type(8)));
typedef float f32x4 __attribute__((ext_vector_type(4)));

__device__ __forceinline__ float bf2f(ushort_t u) {
    return __uint_as_float(((unsigned int)u) << 16);
}
__device__ __forceinline__ ushort_t f2bf(float x) {
    unsigned int u = __float_as_uint(x);
    unsigned int r = u + 0x7fffu + ((u >> 16) & 1u);   // round-to-nearest-even
    return (ushort_t)(r >> 16);
}

// ---------------------------------------------------------------------------
// Kernel 1: cast x (fp32, T*B*Cin) -> bf16 with a BATCH*CINCH zero prefix
// ---------------------------------------------------------------------------
__global__ void cast_x_kernel(const float* __restrict__ x, ushort_t* __restrict__ xb) {
    int i = blockIdx.x * 256 + threadIdx.x;
    int e = i * 4;
    ushort4 r;
    if (e < BATCH * CINCH) {
        r.x = 0; r.y = 0; r.z = 0; r.w = 0;
    } else {
        float4 v = *(const float4*)(x + (e - BATCH * CINCH));
        r.x = f2bf(v.x); r.y = f2bf(v.y); r.z = f2bf(v.z); r.w = f2bf(v.w);
    }
    *(ushort4*)(xb + e) = r;
}

// ---------------------------------------------------------------------------
// Kernel 2: repack W (3H, Cin, K=2) fp32 -> Wb (3H, 1024) bf16
// ---------------------------------------------------------------------------
__global__ void repack_w_kernel(const float* __restrict__ W, ushort_t* __restrict__ wb) {
    int i = blockIdx.x * 256 + threadIdx.x;
    int o  = i >> 10;
    int r  = i & 1023;
    int k  = r >> 9;
    int ci = r & 511;
    wb[i] = f2bf(W[o * 1024 + ci * 2 + k]);
}

// ---------------------------------------------------------------------------
// Kernel 3: GEMM + bias + activation (round-0 structure: 128x128 tile, BK=64,
// 4 waves, 16x16x32 MFMA, XOR-swizzled LDS-A, global_load_lds width=16).
// ONE change vs round-0: B streams L2 -> registers (double-buffered across
// K-tiles, named reg banks), removing B's LDS reads + staging writes.
// ---------------------------------------------------------------------------
__device__ __forceinline__ void load_lds_16B(const ushort_t* g, ushort_t* l) {
    auto* gp = reinterpret_cast<const __attribute__((address_space(1))) unsigned int*>(
        reinterpret_cast<uintptr_t>(g));
    auto* lp = reinterpret_cast<__attribute__((address_space(3))) unsigned int*>(
        reinterpret_cast<uintptr_t>(l));
    __builtin_amdgcn_global_load_lds(gp, lp, 16, 0, 0);
}

__device__ __forceinline__ bf16x8 bload(const ushort_t* p) {
    return __builtin_bit_cast(bf16x8, *(const u16x8*)(p));
}

__global__ __launch_bounds__(256) void gemm_gates_kernel(
    const ushort_t* __restrict__ xb, const ushort_t* __restrict__ wb,
    const float* __restrict__ bias,
    ushort_t* __restrict__ zb, ushort_t* __restrict__ fb, ushort_t* __restrict__ ob) {

    __shared__ ushort_t smem[128 * 128];   // 32 KB: As (first 16 KB) in K-loop; out-tile in epilogue
    ushort_t* As = smem;

    const int tid  = threadIdx.x;
    const int w    = tid >> 6;
    const int lane = tid & 63;
    const int quad = lane >> 4;
    const int l15  = lane & 15;
    const int wm   = w & 1;
    const int wn   = w >> 1;
    const int mBase = blockIdx.x * 128;
    const int nBase = blockIdx.y * 128;

    const int srow = lane >> 3;
    const int scb  = lane & 7;

    // B per-lane base element offset (row = nBase + wn*64 + nt*16 + l15)
    const ushort_t* bbase = wb + (long)(nBase + wn * 64 + l15) * 1024 + quad * 8;

    f32x4 acc[4][4];
#pragma unroll
    for (int i = 0; i < 4; ++i)
#pragma unroll
        for (int j = 0; j < 4; ++j)
            acc[i][j] = (f32x4){0.f, 0.f, 0.f, 0.f};

    bf16x8 bc0[4], bc1[4], bn0[4], bn1[4];

    // Prologue: issue B(0) into the "current" bank
#pragma unroll
    for (int nt = 0; nt < 4; ++nt) {
        bc0[nt] = bload(bbase + nt * 16384);
        bc1[nt] = bload(bbase + nt * 16384 + 32);
    }

    for (int kt = 0; kt < 16; kt += 2) {
        // ================= even tile: consume bc*, prefetch bn* = B(kt+1)
        __syncthreads();
        {
            const long aOff = (kt < 8) ? (long)kt * 64 : (long)16 * 512 + (long)(kt - 8) * 64;
#pragma unroll
            for (int i = 0; i < 4; ++i) {
                const int row = w * 32 + i * 8 + srow;
                const int cbd = scb ^ (row & 7);
                load_lds_16B(xb + (long)(mBase + row) * 512 + aOff + cbd * 8,
                             &As[(w * 32 + i * 8) * 64]);
            }
        }
        __syncthreads();
#pragma unroll
        for (int nt = 0; nt < 4; ++nt) {
            bn0[nt] = bload(bbase + nt * 16384 + (kt + 1) * 64);
            bn1[nt] = bload(bbase + nt * 16384 + (kt + 1) * 64 + 32);
        }
#pragma unroll
        for (int ks = 0; ks < 2; ++ks) {
            bf16x8 af[4];
            const int cbd = ks * 4 + quad;
#pragma unroll
            for (int mt = 0; mt < 4; ++mt) {
                int ml  = wm * 64 + mt * 16 + l15;
                int off = ml * 64 + ((cbd ^ (ml & 7)) * 8);
                af[mt] = __builtin_bit_cast(bf16x8, *(const u16x8*)(&As[off]));
            }
#pragma unroll
            for (int mt = 0; mt < 4; ++mt)
#pragma unroll
                for (int nt = 0; nt < 4; ++nt)
                    acc[mt][nt] = __builtin_amdgcn_mfma_f32_16x16x32_bf16(
                        af[mt], (ks == 0) ? bc0[nt] : bc1[nt], acc[mt][nt], 0, 0, 0);
        }

        // ================= odd tile: consume bn*, prefetch bc* = B(kt+2)
        __syncthreads();
        {
            const int ko = kt + 1;
            const long aOff = (ko < 8) ? (long)ko * 64 : (long)16 * 512 + (long)(ko - 8) * 64;
#pragma unroll
            for (int i = 0; i < 4; ++i) {
                const int row = w * 32 + i * 8 + srow;
                const int cbd = scb ^ (row & 7);
                load_lds_16B(xb + (long)(mBase + row) * 512 + aOff + cbd * 8,
                             &As[(w * 32 + i * 8) * 64]);
            }
        }
        __syncthreads();
        if (kt + 2 < 16) {
#pragma unroll
            for (int nt = 0; nt < 4; ++nt) {
                bc0[nt] = bload(bbase + nt * 16384 + (kt + 2) * 64);
                bc1[nt] = bload(bbase + nt * 16384 + (kt + 2) * 64 + 32);
            }
        }
#pragma unroll
        for (int ks = 0; ks < 2; ++ks) {
            bf16x8 af[4];
            const int cbd = ks * 4 + quad;
#pragma unroll
            for (int mt = 0; mt < 4; ++mt) {
                int ml  = wm * 64 + mt * 16 + l15;
                int off = ml * 64 + ((cbd ^ (ml & 7)) * 8);
                af[mt] = __builtin_bit_cast(bf16x8, *(const u16x8*)(&As[off]));
            }
#pragma unroll
            for (int mt = 0; mt < 4; ++mt)
#pragma unroll
                for (int nt = 0; nt < 4; ++nt)
                    acc[mt][nt] = __builtin_amdgcn_mfma_f32_16x16x32_bf16(
                        af[mt], (ks == 0) ? bn0[nt] : bn1[nt], acc[mt][nt], 0, 0, 0);
        }
    }

    // ---- Epilogue: bias + activation into LDS (swizzled), then coalesced stores
    const int gate = nBase >> 9;            // block-uniform: 4 N-tiles per gate
    const int hb   = nBase & 511;

    __syncthreads();   // everyone done reading As
#pragma unroll
    for (int nt = 0; nt < 4; ++nt) {
        const int n_local = wn * 64 + nt * 16 + l15;
        const float bv = bias[nBase + n_local];
#pragma unroll
        for (int mt = 0; mt < 4; ++mt) {
#pragma unroll
            for (int r = 0; r < 4; ++r) {
                const int m_local = wm * 64 + mt * 16 + quad * 4 + r;
                float g = acc[mt][nt][r] + bv;
                float a;
                if (gate == 0) {
                    float e = __expf(-2.f * fabsf(g));
                    float t = (1.f - e) / (1.f + e);
                    a = copysignf(t, g);
                } else {
                    a = 1.f / (1.f + __expf(-g));
                }
                const int phys = ((n_local >> 3) ^ (m_local & 7)) * 8 + (n_local & 7);
                smem[m_local * 128 + phys] = f2bf(a);
            }
        }
    }
    __syncthreads();

    ushort_t* outp = (gate == 0) ? zb : (gate == 1) ? fb : ob;
#pragma unroll
    for (int s = 0; s < 8; ++s) {
        const int m_local = w * 32 + s * 4 + quad;
        const int blk = l15 ^ (m_local & 7);   // phys block holding logical block l15
        u16x8 v = *(const u16x8*)(&smem[m_local * 128 + blk * 8]);
        *(u16x8*)(outp + (long)(mBase + m_local) * 512 + hb + l15 * 8) = v;
    }
}

// ---------------------------------------------------------------------------
// Scan, chunked-parallel (3 passes), vec4 columns (8B bf16 loads, 16B stores).
// ---------------------------------------------------------------------------
__device__ __forceinline__ void scan_step(float z, float f, float& A, float& Bv) {
    Bv = f * Bv + (1.f - f) * z;
    A *= f;
}

__global__ __launch_bounds__(256) void scan_compose(
    const ushort_t* __restrict__ zb, const ushort_t* __restrict__ fb,
    float* __restrict__ Acomp, float* __restrict__ Bcomp) {
    const int cg  = (blockIdx.x & 7) * 256 + threadIdx.x;   // 2048 col-groups/chunk
    const int ch  = blockIdx.x >> 3;
    const int col = cg * 4;
    const long base = (long)ch * CHL * NCOL + col;
    float Ax = 1.f, Ay = 1.f, Az = 1.f, Aw = 1.f;
    float Bx = 0.f, By = 0.f, Bz = 0.f, Bw = 0.f;
    const int U = 8;
    for (int w0 = 0; w0 < CHL; w0 += U) {
        ushort4 zr[U], fr[U];
#pragma unroll
        for (int u = 0; u < U; ++u) {
            const long idx = base + (long)(w0 + u) * NCOL;
            zr[u] = *(const ushort4*)(zb + idx);
            fr[u] = *(const ushort4*)(fb + idx);
        }
#pragma unroll
        for (int u = 0; u < U; ++u) {
            scan_step(bf2f(zr[u].x), bf2f(fr[u].x), Ax, Bx);
            scan_step(bf2f(zr[u].y), bf2f(fr[u].y), Ay, By);
            scan_step(bf2f(zr[u].z), bf2f(fr[u].z), Az, Bz);
            scan_step(bf2f(zr[u].w), bf2f(fr[u].w), Aw, Bw);
        }
    }
    *(float4*)(Acomp + (long)ch * NCOL + col) = make_float4(Ax, Ay, Az, Aw);
    *(float4*)(Bcomp + (long)ch * NCOL + col) = make_float4(Bx, By, Bz, Bw);
}

__global__ void scan_prefix(const float* __restrict__ Acomp,
                            const float* __restrict__ Bcomp,
                            float* __restrict__ Cin) {
    const int col = blockIdx.x * 256 + threadIdx.x;
    float c = 0.f;
#pragma unroll 4
    for (int ch = 0; ch < NCH; ++ch) {
        Cin[ch * NCOL + col] = c;
        c = Acomp[ch * NCOL + col] * c + Bcomp[ch * NCOL + col];
    }
}

__global__ __launch_bounds__(256) void scan_apply(
    const ushort_t* __restrict__ zb, const ushort_t* __restrict__ fb,
    const ushort_t* __restrict__ ob, const float* __restrict__ Cin,
    float* __restrict__ out) {
    const int cg  = (blockIdx.x & 7) * 256 + threadIdx.x;
    const int ch  = blockIdx.x >> 3;
    const int col = cg * 4;
    const long base = (long)ch * CHL * NCOL + col;
    float4 c0 = *(const float4*)(Cin + (long)ch * NCOL + col);
    float cx = c0.x, cy = c0.y, cz = c0.z, cw = c0.w;
    float hx = 0.f, hy = 0.f, hz = 0.f, hw = 0.f;
    const int U = 8;
    for (int w0 = 0; w0 < CHL; w0 += U) {
        ushort4 zr[U], fr[U], orr[U];
#pragma unroll
        for (int u = 0; u < U; ++u) {
            const long idx = base + (long)(w0 + u) * NCOL;
            zr[u]  = *(const ushort4*)(zb + idx);
            fr[u]  = *(const ushort4*)(fb + idx);
            orr[u] = *(const ushort4*)(ob + idx);
        }
#pragma unroll
        for (int u = 0; u < U; ++u) {
            float f, z;
            f = bf2f(fr[u].x); z = bf2f(zr[u].x); cx = f * cx + (1.f - f) * z; hx = cx * bf2f(orr[u].x);
            f = bf2f(fr[u].y); z = bf2f(zr[u].y); cy = f * cy + (1.f - f) * z; hy = cy * bf2f(orr[u].y);
            f = bf2f(fr[u].z); z = bf2f(zr[u].z); cz = f * cz + (1.f - f) * z; hz = cz * bf2f(orr[u].z);
            f = bf2f(fr[u].w); z = bf2f(zr[u].w); cw = f * cw + (1.f - f) * z; hw = cw * bf2f(orr[u].w);
            *(float4*)(out + base + (long)(w0 + u) * NCOL) = make_float4(hx, hy, hz, hw);
        }
    }
    if (ch == NCH - 1) {
        *(float4*)(out + (long)SEQ * NCOL + col)        = make_float4(hx, hy, hz, hw);  // h_last
        *(float4*)(out + (long)SEQ * NCOL + NCOL + col) = make_float4(cx, cy, cz, cw);  // c_last
    }
}

// ---------------------------------------------------------------------------
extern "C" void kernel_launch(void* const* d_in, const int* in_sizes, int n_in,
                              void* d_out, int out_size, void* d_ws, size_t ws_size,
                              hipStream_t stream) {
    const float* x  = (const float*)d_in[0];   // (T, B, Cin)
    const float* W  = (const float*)d_in[1];   // (3H, Cin, 2)
    const float* bi = (const float*)d_in[2];   // (3H,)
    float* out = (float*)d_out;

    char* ws = (char*)d_ws;
    const size_t xbN = (size_t)(TBM + BATCH) * CINCH;   // padded bf16 x
    const size_t wbN = (size_t)NDIM * KRED;
    const size_t gN  = (size_t)TBM * HDIM;
    ushort_t* xb = (ushort_t*)ws;
    ushort_t* wb = (ushort_t*)(ws + xbN * 2);
    ushort_t* zb = (ushort_t*)(ws + xbN * 2 + wbN * 2);
    ushort_t* fb = zb + gN;
    ushort_t* ob = fb + gN;
    // scan scratch reuses the xb region (dead after the GEMM)
    float* Acomp = (float*)ws;
    float* Bcomp = Acomp + NCH * NCOL;
    float* Cin   = Bcomp + NCH * NCOL;

    cast_x_kernel<<<16392, 256, 0, stream>>>(x, xb);
    repack_w_kernel<<<6144, 256, 0, stream>>>(W, wb);
    dim3 ggrid(TBM / 128, NDIM / 128);
    gemm_gates_kernel<<<ggrid, 256, 0, stream>>>(xb, wb, bi, zb, fb, ob);
    scan_compose<<<NCH * 8, 256, 0, stream>>>(zb, fb, Acomp, Bcomp);
    scan_prefix<<<NCOL / 256, 256, 0, stream>>>(Acomp, Bcomp, Cin);
    scan_apply<<<NCH * 8, 256, 0, stream>>>(zb, fb, ob, Cin, out);
}

// Round 6
// 298.573 us; speedup vs baseline: 1.3323x; 1.3323x over previous
//
#include <hip/hip_runtime.h>

// Problem constants
#define SEQ   2048
#define BATCH 16
#define CINCH 512
#define HDIM  512
#define NDIM  1536            // 3*H
#define TBM   (SEQ*BATCH)     // 32768 = GEMM M
#define KRED  1024            // Cin*K = GEMM K
#define NCH   64              // scan chunks (was 32: 256 blocks = 1/CU was latency-bound)
#define CHL   32              // chunk length (NCH*CHL == SEQ)
#define NCOL  8192            // B*H chains

typedef unsigned short ushort_t;
typedef __bf16 bf16x8 __attribute__((ext_vector_type(8)));
typedef unsigned short u16x8 __attribute__((ext_vector_type(8)));
typedef float f32x4 __attribute__((ext_vector_type(4)));

__device__ __forceinline__ float bf2f(ushort_t u) {
    return __uint_as_float(((unsigned int)u) << 16);
}
__device__ __forceinline__ ushort_t f2bf(float x) {
    unsigned int u = __float_as_uint(x);
    unsigned int r = u + 0x7fffu + ((u >> 16) & 1u);   // round-to-nearest-even
    return (ushort_t)(r >> 16);
}

// ---------------------------------------------------------------------------
// Kernel 1: cast x (fp32, T*B*Cin) -> bf16 with a BATCH*CINCH zero prefix so
// row m of the "concat" A-matrix is [xbpad row m (t-1 tap), xbpad row m+B (t tap)]
// ---------------------------------------------------------------------------
__global__ void cast_x_kernel(const float* __restrict__ x, ushort_t* __restrict__ xb) {
    int i = blockIdx.x * 256 + threadIdx.x;
    int e = i * 4;
    ushort4 r;
    if (e < BATCH * CINCH) {
        r.x = 0; r.y = 0; r.z = 0; r.w = 0;
    } else {
        float4 v = *(const float4*)(x + (e - BATCH * CINCH));
        r.x = f2bf(v.x); r.y = f2bf(v.y); r.z = f2bf(v.z); r.w = f2bf(v.w);
    }
    *(ushort4*)(xb + e) = r;
}

// ---------------------------------------------------------------------------
// Kernel 2: repack W (3H, Cin, K=2) fp32 -> Wb (3H, 1024) bf16 where
// Wb[o][k*512+ci] = W[o][ci][k]
// ---------------------------------------------------------------------------
__global__ void repack_w_kernel(const float* __restrict__ W, ushort_t* __restrict__ wb) {
    int i = blockIdx.x * 256 + threadIdx.x;
    int o  = i >> 10;
    int r  = i & 1023;
    int k  = r >> 9;
    int ci = r & 511;
    wb[i] = f2bf(W[o * 1024 + ci * 2 + k]);
}

// ---------------------------------------------------------------------------
// Kernel 3: GEMM + bias + activation -> bf16 gates z/f/o, each [T*B][H].
// MEASURED-GOOD round-0 structure (133 us, MfmaUtil 34.5%): 128x128 tile,
// BK=64, 4 waves, 16x16x32 bf16 MFMA, XOR-swizzled LDS, global_load_lds
// width=16 staging for BOTH A and B. Do not restructure: B-in-register
// variants measured 204 us (256^2) and 286 us (128^2) — L2 latency exposed
// at every barrier beats the LDS-pipe cost of staging B.
// ---------------------------------------------------------------------------
__device__ __forceinline__ void load_lds_16B(const ushort_t* g, ushort_t* l) {
    auto* gp = reinterpret_cast<const __attribute__((address_space(1))) unsigned int*>(
        reinterpret_cast<uintptr_t>(g));
    auto* lp = reinterpret_cast<__attribute__((address_space(3))) unsigned int*>(
        reinterpret_cast<uintptr_t>(l));
    __builtin_amdgcn_global_load_lds(gp, lp, 16, 0, 0);
}

__global__ __launch_bounds__(256) void gemm_gates_kernel(
    const ushort_t* __restrict__ xb, const ushort_t* __restrict__ wb,
    const float* __restrict__ bias,
    ushort_t* __restrict__ zb, ushort_t* __restrict__ fb, ushort_t* __restrict__ ob) {

    __shared__ ushort_t smem[2 * 128 * 64];   // As/Bs during K-loop; 128x128 out-tile in epilogue
    ushort_t* As = smem;
    ushort_t* Bs = smem + 128 * 64;

    const int tid  = threadIdx.x;
    const int w    = tid >> 6;
    const int lane = tid & 63;
    const int quad = lane >> 4;
    const int l15  = lane & 15;
    const int wm   = w & 1;
    const int wn   = w >> 1;
    const int mBase = blockIdx.x * 128;
    const int nBase = blockIdx.y * 128;

    const int srow = lane >> 3;
    const int scb  = lane & 7;

    f32x4 acc[4][4];
#pragma unroll
    for (int i = 0; i < 4; ++i)
#pragma unroll
        for (int j = 0; j < 4; ++j)
            acc[i][j] = (f32x4){0.f, 0.f, 0.f, 0.f};

    for (int kt = 0; kt < 16; ++kt) {
        __syncthreads();
        const long aOff = (kt < 8) ? (long)kt * 64 : (long)16 * 512 + (long)(kt - 8) * 64;
#pragma unroll
        for (int i = 0; i < 4; ++i) {
            const int row = w * 32 + i * 8 + srow;
            const int cbd = scb ^ (row & 7);
            const ushort_t* ga = xb + (long)(mBase + row) * 512 + aOff + cbd * 8;
            load_lds_16B(ga, &As[(w * 32 + i * 8) * 64]);
            const ushort_t* gb = wb + (long)(nBase + row) * 1024 + kt * 64 + cbd * 8;
            load_lds_16B(gb, &Bs[(w * 32 + i * 8) * 64]);
        }
        __syncthreads();

#pragma unroll
        for (int ks = 0; ks < 2; ++ks) {
            bf16x8 af[4], bfr[4];
            const int cbd = ks * 4 + quad;
#pragma unroll
            for (int mt = 0; mt < 4; ++mt) {
                int ml  = wm * 64 + mt * 16 + l15;
                int off = ml * 64 + ((cbd ^ (ml & 7)) * 8);
                af[mt] = __builtin_bit_cast(bf16x8, *(const u16x8*)(&As[off]));
            }
#pragma unroll
            for (int nt = 0; nt < 4; ++nt) {
                int nl  = wn * 64 + nt * 16 + l15;
                int off = nl * 64 + ((cbd ^ (nl & 7)) * 8);
                bfr[nt] = __builtin_bit_cast(bf16x8, *(const u16x8*)(&Bs[off]));
            }
#pragma unroll
            for (int mt = 0; mt < 4; ++mt)
#pragma unroll
                for (int nt = 0; nt < 4; ++nt)
                    acc[mt][nt] = __builtin_amdgcn_mfma_f32_16x16x32_bf16(
                        af[mt], bfr[nt], acc[mt][nt], 0, 0, 0);
        }
    }

    // ---- Epilogue: bias + activation into LDS (swizzled), then coalesced stores
    const int gate = nBase >> 9;            // block-uniform: 4 N-tiles per gate
    const int hb   = nBase & 511;

    __syncthreads();   // everyone done reading As/Bs
#pragma unroll
    for (int nt = 0; nt < 4; ++nt) {
        const int n_local = wn * 64 + nt * 16 + l15;
        const float bv = bias[nBase + n_local];
#pragma unroll
        for (int mt = 0; mt < 4; ++mt) {
#pragma unroll
            for (int r = 0; r < 4; ++r) {
                const int m_local = wm * 64 + mt * 16 + quad * 4 + r;
                float g = acc[mt][nt][r] + bv;
                float a;
                if (gate == 0) {
                    float e = __expf(-2.f * fabsf(g));
                    float t = (1.f - e) / (1.f + e);
                    a = copysignf(t, g);
                } else {
                    a = 1.f / (1.f + __expf(-g));
                }
                const int phys = ((n_local >> 3) ^ (m_local & 7)) * 8 + (n_local & 7);
                smem[m_local * 128 + phys] = f2bf(a);
            }
        }
    }
    __syncthreads();

    ushort_t* outp = (gate == 0) ? zb : (gate == 1) ? fb : ob;
#pragma unroll
    for (int s = 0; s < 8; ++s) {
        const int m_local = w * 32 + s * 4 + quad;
        const int blk = l15 ^ (m_local & 7);   // phys block holding logical block l15
        u16x8 v = *(const u16x8*)(&smem[m_local * 128 + blk * 8]);
        *(u16x8*)(outp + (long)(mBase + m_local) * 512 + hb + l15 * 8) = v;
    }
}

// ---------------------------------------------------------------------------
// Scan, chunked-parallel (3 passes), vec4 columns (8B bf16 loads, 16B stores).
// NCH=64 doubles the compose/apply grids to 512 blocks (2 blocks/CU).
// ---------------------------------------------------------------------------
__device__ __forceinline__ void scan_step(float z, float f, float& A, float& Bv) {
    Bv = f * Bv + (1.f - f) * z;
    A *= f;
}

__global__ __launch_bounds__(256) void scan_compose(
    const ushort_t* __restrict__ zb, const ushort_t* __restrict__ fb,
    float* __restrict__ Acomp, float* __restrict__ Bcomp) {
    const int cg  = (blockIdx.x & 7) * 256 + threadIdx.x;   // 2048 col-groups/chunk
    const int ch  = blockIdx.x >> 3;
    const int col = cg * 4;
    const long base = (long)ch * CHL * NCOL + col;
    float Ax = 1.f, Ay = 1.f, Az = 1.f, Aw = 1.f;
    float Bx = 0.f, By = 0.f, Bz = 0.f, Bw = 0.f;
    const int U = 8;
    for (int w0 = 0; w0 < CHL; w0 += U) {
        ushort4 zr[U], fr[U];
#pragma unroll
        for (int u = 0; u < U; ++u) {
            const long idx = base + (long)(w0 + u) * NCOL;
            zr[u] = *(const ushort4*)(zb + idx);
            fr[u] = *(const ushort4*)(fb + idx);
        }
#pragma unroll
        for (int u = 0; u < U; ++u) {
            scan_step(bf2f(zr[u].x), bf2f(fr[u].x), Ax, Bx);
            scan_step(bf2f(zr[u].y), bf2f(fr[u].y), Ay, By);
            scan_step(bf2f(zr[u].z), bf2f(fr[u].z), Az, Bz);
            scan_step(bf2f(zr[u].w), bf2f(fr[u].w), Aw, Bw);
        }
    }
    *(float4*)(Acomp + (long)ch * NCOL + col) = make_float4(Ax, Ay, Az, Aw);
    *(float4*)(Bcomp + (long)ch * NCOL + col) = make_float4(Bx, By, Bz, Bw);
}

__global__ void scan_prefix(const float* __restrict__ Acomp,
                            const float* __restrict__ Bcomp,
                            float* __restrict__ Cin) {
    const int col = blockIdx.x * 256 + threadIdx.x;
    float c = 0.f;
#pragma unroll 4
    for (int ch = 0; ch < NCH; ++ch) {
        Cin[ch * NCOL + col] = c;
        c = Acomp[ch * NCOL + col] * c + Bcomp[ch * NCOL + col];
    }
}

__global__ __launch_bounds__(256) void scan_apply(
    const ushort_t* __restrict__ zb, const ushort_t* __restrict__ fb,
    const ushort_t* __restrict__ ob, const float* __restrict__ Cin,
    float* __restrict__ out) {
    const int cg  = (blockIdx.x & 7) * 256 + threadIdx.x;
    const int ch  = blockIdx.x >> 3;
    const int col = cg * 4;
    const long base = (long)ch * CHL * NCOL + col;
    float4 c0 = *(const float4*)(Cin + (long)ch * NCOL + col);
    float cx = c0.x, cy = c0.y, cz = c0.z, cw = c0.w;
    float hx = 0.f, hy = 0.f, hz = 0.f, hw = 0.f;
    const int U = 8;
    for (int w0 = 0; w0 < CHL; w0 += U) {
        ushort4 zr[U], fr[U], orr[U];
#pragma unroll
        for (int u = 0; u < U; ++u) {
            const long idx = base + (long)(w0 + u) * NCOL;
            zr[u]  = *(const ushort4*)(zb + idx);
            fr[u]  = *(const ushort4*)(fb + idx);
            orr[u] = *(const ushort4*)(ob + idx);
        }
#pragma unroll
        for (int u = 0; u < U; ++u) {
            float f, z;
            f = bf2f(fr[u].x); z = bf2f(zr[u].x); cx = f * cx + (1.f - f) * z; hx = cx * bf2f(orr[u].x);
            f = bf2f(fr[u].y); z = bf2f(zr[u].y); cy = f * cy + (1.f - f) * z; hy = cy * bf2f(orr[u].y);
            f = bf2f(fr[u].z); z = bf2f(zr[u].z); cz = f * cz + (1.f - f) * z; hz = cz * bf2f(orr[u].z);
            f = bf2f(fr[u].w); z = bf2f(zr[u].w); cw = f * cw + (1.f - f) * z; hw = cw * bf2f(orr[u].w);
            *(float4*)(out + base + (long)(w0 + u) * NCOL) = make_float4(hx, hy, hz, hw);
        }
    }
    if (ch == NCH - 1) {
        *(float4*)(out + (long)SEQ * NCOL + col)        = make_float4(hx, hy, hz, hw);  // h_last
        *(float4*)(out + (long)SEQ * NCOL + NCOL + col) = make_float4(cx, cy, cz, cw);  // c_last
    }
}

// ---------------------------------------------------------------------------
extern "C" void kernel_launch(void* const* d_in, const int* in_sizes, int n_in,
                              void* d_out, int out_size, void* d_ws, size_t ws_size,
                              hipStream_t stream) {
    const float* x  = (const float*)d_in[0];   // (T, B, Cin)
    const float* W  = (const float*)d_in[1];   // (3H, Cin, 2)
    const float* bi = (const float*)d_in[2];   // (3H,)
    float* out = (float*)d_out;

    char* ws = (char*)d_ws;
    const size_t xbN = (size_t)(TBM + BATCH) * CINCH;   // padded bf16 x
    const size_t wbN = (size_t)NDIM * KRED;
    const size_t gN  = (size_t)TBM * HDIM;
    ushort_t* xb = (ushort_t*)ws;
    ushort_t* wb = (ushort_t*)(ws + xbN * 2);
    ushort_t* zb = (ushort_t*)(ws + xbN * 2 + wbN * 2);
    ushort_t* fb = zb + gN;
    ushort_t* ob = fb + gN;
    // scan scratch reuses the xb region (dead after the GEMM): 6 MB << 33.5 MB
    float* Acomp = (float*)ws;
    float* Bcomp = Acomp + NCH * NCOL;
    float* Cin   = Bcomp + NCH * NCOL;

    cast_x_kernel<<<16392, 256, 0, stream>>>(x, xb);
    repack_w_kernel<<<6144, 256, 0, stream>>>(W, wb);
    dim3 ggrid(TBM / 128, NDIM / 128);
    gemm_gates_kernel<<<ggrid, 256, 0, stream>>>(xb, wb, bi, zb, fb, ob);
    scan_compose<<<NCH * 8, 256, 0, stream>>>(zb, fb, Acomp, Bcomp);
    scan_prefix<<<NCOL / 256, 256, 0, stream>>>(Acomp, Bcomp, Cin);
    scan_apply<<<NCH * 8, 256, 0, stream>>>(zb, fb, ob, Cin, out);
}

// Round 8
// 274.150 us; speedup vs baseline: 1.4510x; 1.0891x over previous
//
#include <hip/hip_runtime.h>

// Problem constants
#define SEQ   2048
#define BATCH 16
#define CINCH 512
#define HDIM  512
#define NDIM  1536            // 3*H
#define TBM   (SEQ*BATCH)     // 32768 = GEMM M
#define KRED  1024            // Cin*K = GEMM K
#define NCH   32              // scan chunks (R2-proven; NCH=64 measured worse)
#define CHL   64              // chunk length (NCH*CHL == SEQ)
#define NCOL  8192            // B*H chains

typedef unsigned short ushort_t;
typedef __bf16 bf16x8 __attribute__((ext_vector_type(8)));
typedef unsigned short u16x8 __attribute__((ext_vector_type(8)));
typedef unsigned short u16x4 __attribute__((ext_vector_type(4)));
typedef float f32x4 __attribute__((ext_vector_type(4)));

__device__ __forceinline__ float bf2f(ushort_t u) {
    return __uint_as_float(((unsigned int)u) << 16);
}
__device__ __forceinline__ ushort_t f2bf(float x) {
    unsigned int u = __float_as_uint(x);
    unsigned int r = u + 0x7fffu + ((u >> 16) & 1u);   // round-to-nearest-even
    return (ushort_t)(r >> 16);
}

// ---------------------------------------------------------------------------
// Kernel 1: fused prep — cast x (fp32 -> bf16, with BATCH*CINCH zero prefix)
// and repack W (3H, Cin, 2) -> Wb (3H, 1024), one launch.
// ---------------------------------------------------------------------------
#define CAST_BLOCKS 16392
__global__ void prep_kernel(const float* __restrict__ x, ushort_t* __restrict__ xb,
                            const float* __restrict__ W, ushort_t* __restrict__ wb) {
    if (blockIdx.x < CAST_BLOCKS) {
        int i = blockIdx.x * 256 + threadIdx.x;
        int e = i * 4;
        ushort4 r;
        if (e < BATCH * CINCH) {
            r.x = 0; r.y = 0; r.z = 0; r.w = 0;
        } else {
            float4 v = *(const float4*)(x + (e - BATCH * CINCH));
            r.x = f2bf(v.x); r.y = f2bf(v.y); r.z = f2bf(v.z); r.w = f2bf(v.w);
        }
        *(ushort4*)(xb + e) = r;
    } else {
        int i = (blockIdx.x - CAST_BLOCKS) * 256 + threadIdx.x;
        int o  = i >> 10;
        int r  = i & 1023;
        int k  = r >> 9;
        int ci = r & 511;
        wb[i] = f2bf(W[o * 1024 + ci * 2 + k]);
    }
}

// ---------------------------------------------------------------------------
// Kernel 2: GEMM + bias + activation -> bf16 gates z/f/o, each [T*B][H].
// MEASURED-GOOD champion (133 us, MfmaUtil 34.5%, reproduced R0/R6): 128x128
// tile, BK=64, 4 waves, 16x16x32 bf16 MFMA, XOR-swizzled LDS, global_load_lds
// width=16 staging for BOTH A and B. DO NOT RESTRUCTURE: 256^2 8-phase
// measured 138/205 us; B-in-register variants measured 204/286 us.
// ---------------------------------------------------------------------------
__device__ __forceinline__ void load_lds_16B(const ushort_t* g, ushort_t* l) {
    auto* gp = reinterpret_cast<const __attribute__((address_space(1))) unsigned int*>(
        reinterpret_cast<uintptr_t>(g));
    auto* lp = reinterpret_cast<__attribute__((address_space(3))) unsigned int*>(
        reinterpret_cast<uintptr_t>(l));
    __builtin_amdgcn_global_load_lds(gp, lp, 16, 0, 0);
}

__global__ __launch_bounds__(256) void gemm_gates_kernel(
    const ushort_t* __restrict__ xb, const ushort_t* __restrict__ wb,
    const float* __restrict__ bias,
    ushort_t* __restrict__ zb, ushort_t* __restrict__ fb, ushort_t* __restrict__ ob) {

    __shared__ ushort_t smem[2 * 128 * 64];   // As/Bs during K-loop; 128x128 out-tile in epilogue
    ushort_t* As = smem;
    ushort_t* Bs = smem + 128 * 64;

    const int tid  = threadIdx.x;
    const int w    = tid >> 6;
    const int lane = tid & 63;
    const int quad = lane >> 4;
    const int l15  = lane & 15;
    const int wm   = w & 1;
    const int wn   = w >> 1;
    const int mBase = blockIdx.x * 128;
    const int nBase = blockIdx.y * 128;

    const int srow = lane >> 3;
    const int scb  = lane & 7;

    f32x4 acc[4][4];
#pragma unroll
    for (int i = 0; i < 4; ++i)
#pragma unroll
        for (int j = 0; j < 4; ++j)
            acc[i][j] = (f32x4){0.f, 0.f, 0.f, 0.f};

    for (int kt = 0; kt < 16; ++kt) {
        __syncthreads();
        const long aOff = (kt < 8) ? (long)kt * 64 : (long)16 * 512 + (long)(kt - 8) * 64;
#pragma unroll
        for (int i = 0; i < 4; ++i) {
            const int row = w * 32 + i * 8 + srow;
            const int cbd = scb ^ (row & 7);
            const ushort_t* ga = xb + (long)(mBase + row) * 512 + aOff + cbd * 8;
            load_lds_16B(ga, &As[(w * 32 + i * 8) * 64]);
            const ushort_t* gb = wb + (long)(nBase + row) * 1024 + kt * 64 + cbd * 8;
            load_lds_16B(gb, &Bs[(w * 32 + i * 8) * 64]);
        }
        __syncthreads();

#pragma unroll
        for (int ks = 0; ks < 2; ++ks) {
            bf16x8 af[4], bfr[4];
            const int cbd = ks * 4 + quad;
#pragma unroll
            for (int mt = 0; mt < 4; ++mt) {
                int ml  = wm * 64 + mt * 16 + l15;
                int off = ml * 64 + ((cbd ^ (ml & 7)) * 8);
                af[mt] = __builtin_bit_cast(bf16x8, *(const u16x8*)(&As[off]));
            }
#pragma unroll
            for (int nt = 0; nt < 4; ++nt) {
                int nl  = wn * 64 + nt * 16 + l15;
                int off = nl * 64 + ((cbd ^ (nl & 7)) * 8);
                bfr[nt] = __builtin_bit_cast(bf16x8, *(const u16x8*)(&Bs[off]));
            }
#pragma unroll
            for (int mt = 0; mt < 4; ++mt)
#pragma unroll
                for (int nt = 0; nt < 4; ++nt)
                    acc[mt][nt] = __builtin_amdgcn_mfma_f32_16x16x32_bf16(
                        af[mt], bfr[nt], acc[mt][nt], 0, 0, 0);
        }
    }

    // ---- Epilogue: bias + activation into LDS (swizzled), then coalesced stores
    const int gate = nBase >> 9;            // block-uniform: 4 N-tiles per gate
    const int hb   = nBase & 511;

    __syncthreads();   // everyone done reading As/Bs
#pragma unroll
    for (int nt = 0; nt < 4; ++nt) {
        const int n_local = wn * 64 + nt * 16 + l15;
        const float bv = bias[nBase + n_local];
#pragma unroll
        for (int mt = 0; mt < 4; ++mt) {
#pragma unroll
            for (int r = 0; r < 4; ++r) {
                const int m_local = wm * 64 + mt * 16 + quad * 4 + r;
                float g = acc[mt][nt][r] + bv;
                float a;
                if (gate == 0) {
                    float e = __expf(-2.f * fabsf(g));
                    float t = (1.f - e) / (1.f + e);
                    a = copysignf(t, g);
                } else {
                    a = 1.f / (1.f + __expf(-g));
                }
                const int phys = ((n_local >> 3) ^ (m_local & 7)) * 8 + (n_local & 7);
                smem[m_local * 128 + phys] = f2bf(a);
            }
        }
    }
    __syncthreads();

    ushort_t* outp = (gate == 0) ? zb : (gate == 1) ? fb : ob;
#pragma unroll
    for (int s = 0; s < 8; ++s) {
        const int m_local = w * 32 + s * 4 + quad;
        const int blk = l15 ^ (m_local & 7);   // phys block holding logical block l15
        u16x8 v = *(const u16x8*)(&smem[m_local * 128 + blk * 8]);
        *(u16x8*)(outp + (long)(mBase + m_local) * 512 + hb + l15 * 8) = v;
    }
}

// ---------------------------------------------------------------------------
// Scan, chunked-parallel, TWO passes (prefix fused into apply):
//   compose: per-chunk (A,B) composition -> Acomp/Bcomp (2 MB, L2-resident)
//   apply:   local exclusive prefix over Acomp/Bcomp (<=31 L2-hit steps,
//            identical math/order to the old scan_prefix), then apply+write.
// ---------------------------------------------------------------------------
__device__ __forceinline__ void scan_step(float z, float f, float& A, float& Bv) {
    Bv = f * Bv + (1.f - f) * z;
    A *= f;
}

__device__ __forceinline__ u16x4 ntload_u4(const ushort_t* p) {
    return __builtin_nontemporal_load((const u16x4*)p);
}

__global__ __launch_bounds__(256) void scan_compose(
    const ushort_t* __restrict__ zb, const ushort_t* __restrict__ fb,
    float* __restrict__ Acomp, float* __restrict__ Bcomp) {
    const int cg  = (blockIdx.x & 7) * 256 + threadIdx.x;   // 2048 col-groups/chunk
    const int ch  = blockIdx.x >> 3;
    const int col = cg * 4;
    const long base = (long)ch * CHL * NCOL + col;
    float Ax = 1.f, Ay = 1.f, Az = 1.f, Aw = 1.f;
    float Bx = 0.f, By = 0.f, Bz = 0.f, Bw = 0.f;
    const int U = 8;
    for (int w0 = 0; w0 < CHL; w0 += U) {
        u16x4 zr[U], fr[U];
#pragma unroll
        for (int u = 0; u < U; ++u) {
            const long idx = base + (long)(w0 + u) * NCOL;
            zr[u] = *(const u16x4*)(zb + idx);
            fr[u] = *(const u16x4*)(fb + idx);
        }
#pragma unroll
        for (int u = 0; u < U; ++u) {
            scan_step(bf2f(zr[u][0]), bf2f(fr[u][0]), Ax, Bx);
            scan_step(bf2f(zr[u][1]), bf2f(fr[u][1]), Ay, By);
            scan_step(bf2f(zr[u][2]), bf2f(fr[u][2]), Az, Bz);
            scan_step(bf2f(zr[u][3]), bf2f(fr[u][3]), Aw, Bw);
        }
    }
    *(f32x4*)(Acomp + (long)ch * NCOL + col) = (f32x4){Ax, Ay, Az, Aw};
    *(f32x4*)(Bcomp + (long)ch * NCOL + col) = (f32x4){Bx, By, Bz, Bw};
}

__global__ __launch_bounds__(256) void scan_apply(
    const ushort_t* __restrict__ zb, const ushort_t* __restrict__ fb,
    const ushort_t* __restrict__ ob,
    const float* __restrict__ Acomp, const float* __restrict__ Bcomp,
    float* __restrict__ out) {
    const int cg  = (blockIdx.x & 7) * 256 + threadIdx.x;
    const int ch  = blockIdx.x >> 3;
    const int col = cg * 4;
    const long base = (long)ch * CHL * NCOL + col;

    // local exclusive prefix over the chunk-compose results (L2-hit; 2 MB total)
    float cx = 0.f, cy = 0.f, cz = 0.f, cw = 0.f;
    for (int k = 0; k < ch; ++k) {
        f32x4 a4 = *(const f32x4*)(Acomp + (long)k * NCOL + col);
        f32x4 b4 = *(const f32x4*)(Bcomp + (long)k * NCOL + col);
        cx = a4[0] * cx + b4[0];
        cy = a4[1] * cy + b4[1];
        cz = a4[2] * cz + b4[2];
        cw = a4[3] * cw + b4[3];
    }

    float hx = 0.f, hy = 0.f, hz = 0.f, hw = 0.f;
    const int U = 8;
    for (int w0 = 0; w0 < CHL; w0 += U) {
        u16x4 zr[U], fr[U], orr[U];
#pragma unroll
        for (int u = 0; u < U; ++u) {
            const long idx = base + (long)(w0 + u) * NCOL;
            zr[u]  = ntload_u4(zb + idx);
            fr[u]  = ntload_u4(fb + idx);
            orr[u] = ntload_u4(ob + idx);
        }
#pragma unroll
        for (int u = 0; u < U; ++u) {
            float f, z;
            f = bf2f(fr[u][0]); z = bf2f(zr[u][0]); cx = f * cx + (1.f - f) * z; hx = cx * bf2f(orr[u][0]);
            f = bf2f(fr[u][1]); z = bf2f(zr[u][1]); cy = f * cy + (1.f - f) * z; hy = cy * bf2f(orr[u][1]);
            f = bf2f(fr[u][2]); z = bf2f(zr[u][2]); cz = f * cz + (1.f - f) * z; hz = cz * bf2f(orr[u][2]);
            f = bf2f(fr[u][3]); z = bf2f(zr[u][3]); cw = f * cw + (1.f - f) * z; hw = cw * bf2f(orr[u][3]);
            f32x4 hv = (f32x4){hx, hy, hz, hw};
            __builtin_nontemporal_store(hv, (f32x4*)(out + base + (long)(w0 + u) * NCOL));
        }
    }
    if (ch == NCH - 1) {
        *(f32x4*)(out + (long)SEQ * NCOL + col)        = (f32x4){hx, hy, hz, hw};  // h_last
        *(f32x4*)(out + (long)SEQ * NCOL + NCOL + col) = (f32x4){cx, cy, cz, cw};  // c_last
    }
}

// ---------------------------------------------------------------------------
extern "C" void kernel_launch(void* const* d_in, const int* in_sizes, int n_in,
                              void* d_out, int out_size, void* d_ws, size_t ws_size,
                              hipStream_t stream) {
    const float* x  = (const float*)d_in[0];   // (T, B, Cin)
    const float* W  = (const float*)d_in[1];   // (3H, Cin, 2)
    const float* bi = (const float*)d_in[2];   // (3H,)
    float* out = (float*)d_out;

    char* ws = (char*)d_ws;
    const size_t xbN = (size_t)(TBM + BATCH) * CINCH;   // padded bf16 x
    const size_t wbN = (size_t)NDIM * KRED;
    const size_t gN  = (size_t)TBM * HDIM;
    ushort_t* xb = (ushort_t*)ws;
    ushort_t* wb = (ushort_t*)(ws + xbN * 2);
    ushort_t* zb = (ushort_t*)(ws + xbN * 2 + wbN * 2);
    ushort_t* fb = zb + gN;
    ushort_t* ob = fb + gN;
    // scan scratch reuses the xb region (dead after the GEMM): 2 MB << 33.5 MB
    float* Acomp = (float*)ws;
    float* Bcomp = Acomp + NCH * NCOL;

    prep_kernel<<<CAST_BLOCKS + 6144, 256, 0, stream>>>(x, xb, W, wb);
    dim3 ggrid(TBM / 128, NDIM / 128);
    gemm_gates_kernel<<<ggrid, 256, 0, stream>>>(xb, wb, bi, zb, fb, ob);
    scan_compose<<<NCH * 8, 256, 0, stream>>>(zb, fb, Acomp, Bcomp);
    scan_apply<<<NCH * 8, 256, 0, stream>>>(zb, fb, ob, Acomp, Bcomp, out);
}

// Round 9
// 272.046 us; speedup vs baseline: 1.4623x; 1.0077x over previous
//
#include <hip/hip_runtime.h>

// Problem constants
#define SEQ   2048
#define BATCH 16
#define CINCH 512
#define HDIM  512
#define NDIM  1536            // 3*H
#define TBM   (SEQ*BATCH)     // 32768 = GEMM M
#define KRED  1024            // Cin*K = GEMM K
#define NCH   32              // scan chunks (R2-proven; NCH=64 measured worse)
#define CHL   64              // chunk length (NCH*CHL == SEQ)
#define NCOL  8192            // B*H chains

typedef unsigned short ushort_t;
typedef __bf16 bf16x8 __attribute__((ext_vector_type(8)));
typedef unsigned short u16x8 __attribute__((ext_vector_type(8)));
typedef unsigned short u16x4 __attribute__((ext_vector_type(4)));
typedef float f32x4 __attribute__((ext_vector_type(4)));

__device__ __forceinline__ float bf2f(ushort_t u) {
    return __uint_as_float(((unsigned int)u) << 16);
}
__device__ __forceinline__ ushort_t f2bf(float x) {
    unsigned int u = __float_as_uint(x);
    unsigned int r = u + 0x7fffu + ((u >> 16) & 1u);   // round-to-nearest-even
    return (ushort_t)(r >> 16);
}

// ---------------------------------------------------------------------------
// Kernel 1: fused prep — cast x (fp32 -> bf16, with BATCH*CINCH zero prefix)
// and repack W (3H, Cin, 2) -> Wb (3H, 1024), one launch. x/W are last-use
// reads -> nontemporal (keep L2 for the xb/wb stores the GEMM reads next).
// ---------------------------------------------------------------------------
#define CAST_BLOCKS 16392
__global__ void prep_kernel(const float* __restrict__ x, ushort_t* __restrict__ xb,
                            const float* __restrict__ W, ushort_t* __restrict__ wb) {
    if (blockIdx.x < CAST_BLOCKS) {
        int i = blockIdx.x * 256 + threadIdx.x;
        int e = i * 4;
        ushort4 r;
        if (e < BATCH * CINCH) {
            r.x = 0; r.y = 0; r.z = 0; r.w = 0;
        } else {
            f32x4 v = __builtin_nontemporal_load((const f32x4*)(x + (e - BATCH * CINCH)));
            r.x = f2bf(v[0]); r.y = f2bf(v[1]); r.z = f2bf(v[2]); r.w = f2bf(v[3]);
        }
        *(ushort4*)(xb + e) = r;
    } else {
        int i = (blockIdx.x - CAST_BLOCKS) * 256 + threadIdx.x;
        int o  = i >> 10;
        int r  = i & 1023;
        int k  = r >> 9;
        int ci = r & 511;
        wb[i] = f2bf(__builtin_nontemporal_load(W + o * 1024 + ci * 2 + k));
    }
}

// ---------------------------------------------------------------------------
// Kernel 2: GEMM + bias + activation -> bf16 gates z/f/o, each [T*B][H].
// MEASURED-GOOD champion (133 us, MfmaUtil 34.5%, reproduced R0/R6): 128x128
// tile, BK=64, 4 waves, 16x16x32 bf16 MFMA, XOR-swizzled LDS, global_load_lds
// width=16 staging for BOTH A and B. DO NOT RESTRUCTURE: 256^2 8-phase
// measured 138/205 us; B-in-register variants measured 204/286 us.
// (R8 measured 167 us with hbm_gbps uniformly -22.5% on identical code —
//  attributed to container memory-state, being re-verified this round.)
// ---------------------------------------------------------------------------
__device__ __forceinline__ void load_lds_16B(const ushort_t* g, ushort_t* l) {
    auto* gp = reinterpret_cast<const __attribute__((address_space(1))) unsigned int*>(
        reinterpret_cast<uintptr_t>(g));
    auto* lp = reinterpret_cast<__attribute__((address_space(3))) unsigned int*>(
        reinterpret_cast<uintptr_t>(l));
    __builtin_amdgcn_global_load_lds(gp, lp, 16, 0, 0);
}

__global__ __launch_bounds__(256) void gemm_gates_kernel(
    const ushort_t* __restrict__ xb, const ushort_t* __restrict__ wb,
    const float* __restrict__ bias,
    ushort_t* __restrict__ zb, ushort_t* __restrict__ fb, ushort_t* __restrict__ ob) {

    __shared__ ushort_t smem[2 * 128 * 64];   // As/Bs during K-loop; 128x128 out-tile in epilogue
    ushort_t* As = smem;
    ushort_t* Bs = smem + 128 * 64;

    const int tid  = threadIdx.x;
    const int w    = tid >> 6;
    const int lane = tid & 63;
    const int quad = lane >> 4;
    const int l15  = lane & 15;
    const int wm   = w & 1;
    const int wn   = w >> 1;
    const int mBase = blockIdx.x * 128;
    const int nBase = blockIdx.y * 128;

    const int srow = lane >> 3;
    const int scb  = lane & 7;

    f32x4 acc[4][4];
#pragma unroll
    for (int i = 0; i < 4; ++i)
#pragma unroll
        for (int j = 0; j < 4; ++j)
            acc[i][j] = (f32x4){0.f, 0.f, 0.f, 0.f};

    for (int kt = 0; kt < 16; ++kt) {
        __syncthreads();
        const long aOff = (kt < 8) ? (long)kt * 64 : (long)16 * 512 + (long)(kt - 8) * 64;
#pragma unroll
        for (int i = 0; i < 4; ++i) {
            const int row = w * 32 + i * 8 + srow;
            const int cbd = scb ^ (row & 7);
            const ushort_t* ga = xb + (long)(mBase + row) * 512 + aOff + cbd * 8;
            load_lds_16B(ga, &As[(w * 32 + i * 8) * 64]);
            const ushort_t* gb = wb + (long)(nBase + row) * 1024 + kt * 64 + cbd * 8;
            load_lds_16B(gb, &Bs[(w * 32 + i * 8) * 64]);
        }
        __syncthreads();

#pragma unroll
        for (int ks = 0; ks < 2; ++ks) {
            bf16x8 af[4], bfr[4];
            const int cbd = ks * 4 + quad;
#pragma unroll
            for (int mt = 0; mt < 4; ++mt) {
                int ml  = wm * 64 + mt * 16 + l15;
                int off = ml * 64 + ((cbd ^ (ml & 7)) * 8);
                af[mt] = __builtin_bit_cast(bf16x8, *(const u16x8*)(&As[off]));
            }
#pragma unroll
            for (int nt = 0; nt < 4; ++nt) {
                int nl  = wn * 64 + nt * 16 + l15;
                int off = nl * 64 + ((cbd ^ (nl & 7)) * 8);
                bfr[nt] = __builtin_bit_cast(bf16x8, *(const u16x8*)(&Bs[off]));
            }
#pragma unroll
            for (int mt = 0; mt < 4; ++mt)
#pragma unroll
                for (int nt = 0; nt < 4; ++nt)
                    acc[mt][nt] = __builtin_amdgcn_mfma_f32_16x16x32_bf16(
                        af[mt], bfr[nt], acc[mt][nt], 0, 0, 0);
        }
    }

    // ---- Epilogue: bias + activation into LDS (swizzled), then coalesced stores
    const int gate = nBase >> 9;            // block-uniform: 4 N-tiles per gate
    const int hb   = nBase & 511;

    __syncthreads();   // everyone done reading As/Bs
#pragma unroll
    for (int nt = 0; nt < 4; ++nt) {
        const int n_local = wn * 64 + nt * 16 + l15;
        const float bv = bias[nBase + n_local];
#pragma unroll
        for (int mt = 0; mt < 4; ++mt) {
#pragma unroll
            for (int r = 0; r < 4; ++r) {
                const int m_local = wm * 64 + mt * 16 + quad * 4 + r;
                float g = acc[mt][nt][r] + bv;
                float a;
                if (gate == 0) {
                    float e = __expf(-2.f * fabsf(g));
                    float t = (1.f - e) / (1.f + e);
                    a = copysignf(t, g);
                } else {
                    a = 1.f / (1.f + __expf(-g));
                }
                const int phys = ((n_local >> 3) ^ (m_local & 7)) * 8 + (n_local & 7);
                smem[m_local * 128 + phys] = f2bf(a);
            }
        }
    }
    __syncthreads();

    ushort_t* outp = (gate == 0) ? zb : (gate == 1) ? fb : ob;
#pragma unroll
    for (int s = 0; s < 8; ++s) {
        const int m_local = w * 32 + s * 4 + quad;
        const int blk = l15 ^ (m_local & 7);   // phys block holding logical block l15
        u16x8 v = *(const u16x8*)(&smem[m_local * 128 + blk * 8]);
        *(u16x8*)(outp + (long)(mBase + m_local) * 512 + hb + l15 * 8) = v;
    }
}

// ---------------------------------------------------------------------------
// Scan, chunked-parallel, TWO passes (prefix fused into apply):
//   compose: per-chunk (A,B) composition -> Acomp/Bcomp (2 MB, L2-resident)
//   apply:   local exclusive prefix over Acomp/Bcomp (<=31 L2-hit steps,
//            identical math/order to the old scan_prefix), then apply+write.
// compose loads stay NORMAL (z/f re-read by apply -> keep in L2); apply
// loads/stores are nontemporal (last use / never re-read).
// ---------------------------------------------------------------------------
__device__ __forceinline__ void scan_step(float z, float f, float& A, float& Bv) {
    Bv = f * Bv + (1.f - f) * z;
    A *= f;
}

__device__ __forceinline__ u16x4 ntload_u4(const ushort_t* p) {
    return __builtin_nontemporal_load((const u16x4*)p);
}

__global__ __launch_bounds__(256) void scan_compose(
    const ushort_t* __restrict__ zb, const ushort_t* __restrict__ fb,
    float* __restrict__ Acomp, float* __restrict__ Bcomp) {
    const int cg  = (blockIdx.x & 7) * 256 + threadIdx.x;   // 2048 col-groups/chunk
    const int ch  = blockIdx.x >> 3;
    const int col = cg * 4;
    const long base = (long)ch * CHL * NCOL + col;
    float Ax = 1.f, Ay = 1.f, Az = 1.f, Aw = 1.f;
    float Bx = 0.f, By = 0.f, Bz = 0.f, Bw = 0.f;
    const int U = 8;
    for (int w0 = 0; w0 < CHL; w0 += U) {
        u16x4 zr[U], fr[U];
#pragma unroll
        for (int u = 0; u < U; ++u) {
            const long idx = base + (long)(w0 + u) * NCOL;
            zr[u] = *(const u16x4*)(zb + idx);
            fr[u] = *(const u16x4*)(fb + idx);
        }
#pragma unroll
        for (int u = 0; u < U; ++u) {
            scan_step(bf2f(zr[u][0]), bf2f(fr[u][0]), Ax, Bx);
            scan_step(bf2f(zr[u][1]), bf2f(fr[u][1]), Ay, By);
            scan_step(bf2f(zr[u][2]), bf2f(fr[u][2]), Az, Bz);
            scan_step(bf2f(zr[u][3]), bf2f(fr[u][3]), Aw, Bw);
        }
    }
    *(f32x4*)(Acomp + (long)ch * NCOL + col) = (f32x4){Ax, Ay, Az, Aw};
    *(f32x4*)(Bcomp + (long)ch * NCOL + col) = (f32x4){Bx, By, Bz, Bw};
}

__global__ __launch_bounds__(256) void scan_apply(
    const ushort_t* __restrict__ zb, const ushort_t* __restrict__ fb,
    const ushort_t* __restrict__ ob,
    const float* __restrict__ Acomp, const float* __restrict__ Bcomp,
    float* __restrict__ out) {
    const int cg  = (blockIdx.x & 7) * 256 + threadIdx.x;
    const int ch  = blockIdx.x >> 3;
    const int col = cg * 4;
    const long base = (long)ch * CHL * NCOL + col;

    // local exclusive prefix over the chunk-compose results (L2-hit; 2 MB total)
    float cx = 0.f, cy = 0.f, cz = 0.f, cw = 0.f;
    for (int k = 0; k < ch; ++k) {
        f32x4 a4 = *(const f32x4*)(Acomp + (long)k * NCOL + col);
        f32x4 b4 = *(const f32x4*)(Bcomp + (long)k * NCOL + col);
        cx = a4[0] * cx + b4[0];
        cy = a4[1] * cy + b4[1];
        cz = a4[2] * cz + b4[2];
        cw = a4[3] * cw + b4[3];
    }

    float hx = 0.f, hy = 0.f, hz = 0.f, hw = 0.f;
    const int U = 8;
    for (int w0 = 0; w0 < CHL; w0 += U) {
        u16x4 zr[U], fr[U], orr[U];
#pragma unroll
        for (int u = 0; u < U; ++u) {
            const long idx = base + (long)(w0 + u) * NCOL;
            zr[u]  = ntload_u4(zb + idx);
            fr[u]  = ntload_u4(fb + idx);
            orr[u] = ntload_u4(ob + idx);
        }
#pragma unroll
        for (int u = 0; u < U; ++u) {
            float f, z;
            f = bf2f(fr[u][0]); z = bf2f(zr[u][0]); cx = f * cx + (1.f - f) * z; hx = cx * bf2f(orr[u][0]);
            f = bf2f(fr[u][1]); z = bf2f(zr[u][1]); cy = f * cy + (1.f - f) * z; hy = cy * bf2f(orr[u][1]);
            f = bf2f(fr[u][2]); z = bf2f(zr[u][2]); cz = f * cz + (1.f - f) * z; hz = cz * bf2f(orr[u][2]);
            f = bf2f(fr[u][3]); z = bf2f(zr[u][3]); cw = f * cw + (1.f - f) * z; hw = cw * bf2f(orr[u][3]);
            f32x4 hv = (f32x4){hx, hy, hz, hw};
            __builtin_nontemporal_store(hv, (f32x4*)(out + base + (long)(w0 + u) * NCOL));
        }
    }
    if (ch == NCH - 1) {
        *(f32x4*)(out + (long)SEQ * NCOL + col)        = (f32x4){hx, hy, hz, hw};  // h_last
        *(f32x4*)(out + (long)SEQ * NCOL + NCOL + col) = (f32x4){cx, cy, cz, cw};  // c_last
    }
}

// ---------------------------------------------------------------------------
extern "C" void kernel_launch(void* const* d_in, const int* in_sizes, int n_in,
                              void* d_out, int out_size, void* d_ws, size_t ws_size,
                              hipStream_t stream) {
    const float* x  = (const float*)d_in[0];   // (T, B, Cin)
    const float* W  = (const float*)d_in[1];   // (3H, Cin, 2)
    const float* bi = (const float*)d_in[2];   // (3H,)
    float* out = (float*)d_out;

    char* ws = (char*)d_ws;
    const size_t xbN = (size_t)(TBM + BATCH) * CINCH;   // padded bf16 x
    const size_t wbN = (size_t)NDIM * KRED;
    const size_t gN  = (size_t)TBM * HDIM;
    ushort_t* xb = (ushort_t*)ws;
    ushort_t* wb = (ushort_t*)(ws + xbN * 2);
    ushort_t* zb = (ushort_t*)(ws + xbN * 2 + wbN * 2);
    ushort_t* fb = zb + gN;
    ushort_t* ob = fb + gN;
    // scan scratch reuses the xb region (dead after the GEMM): 2 MB << 33.5 MB
    float* Acomp = (float*)ws;
    float* Bcomp = Acomp + NCH * NCOL;

    prep_kernel<<<CAST_BLOCKS + 6144, 256, 0, stream>>>(x, xb, W, wb);
    dim3 ggrid(TBM / 128, NDIM / 128);
    gemm_gates_kernel<<<ggrid, 256, 0, stream>>>(xb, wb, bi, zb, fb, ob);
    scan_compose<<<NCH * 8, 256, 0, stream>>>(zb, fb, Acomp, Bcomp);
    scan_apply<<<NCH * 8, 256, 0, stream>>>(zb, fb, ob, Acomp, Bcomp, out);
}

// Round 10
// 267.723 us; speedup vs baseline: 1.4859x; 1.0161x over previous
//
#include <hip/hip_runtime.h>

// Problem constants
#define SEQ   2048
#define BATCH 16
#define CINCH 512
#define HDIM  512
#define NDIM  1536            // 3*H
#define TBM   (SEQ*BATCH)     // 32768 = GEMM M
#define KRED  1024            // Cin*K = GEMM K
#define NCH   32              // scan chunks (R2-proven; NCH=64 measured worse)
#define CHL   64              // chunk length (NCH*CHL == SEQ)
#define NCOL  8192            // B*H chains

typedef unsigned short ushort_t;
typedef __bf16 bf16x8 __attribute__((ext_vector_type(8)));
typedef unsigned short u16x8 __attribute__((ext_vector_type(8)));
typedef unsigned short u16x4 __attribute__((ext_vector_type(4)));
typedef float f32x4 __attribute__((ext_vector_type(4)));

__device__ __forceinline__ float bf2f(ushort_t u) {
    return __uint_as_float(((unsigned int)u) << 16);
}
__device__ __forceinline__ ushort_t f2bf(float x) {
    unsigned int u = __float_as_uint(x);
    unsigned int r = u + 0x7fffu + ((u >> 16) & 1u);   // round-to-nearest-even
    return (ushort_t)(r >> 16);
}

// ---------------------------------------------------------------------------
// Kernel 1: fused prep — cast x (fp32 -> bf16, with BATCH*CINCH zero prefix)
// and repack W (3H, Cin, 2) -> Wb (3H, 1024), one launch. x/W are last-use
// reads -> nontemporal.
// ---------------------------------------------------------------------------
#define CAST_BLOCKS 16392
__global__ void prep_kernel(const float* __restrict__ x, ushort_t* __restrict__ xb,
                            const float* __restrict__ W, ushort_t* __restrict__ wb) {
    if (blockIdx.x < CAST_BLOCKS) {
        int i = blockIdx.x * 256 + threadIdx.x;
        int e = i * 4;
        ushort4 r;
        if (e < BATCH * CINCH) {
            r.x = 0; r.y = 0; r.z = 0; r.w = 0;
        } else {
            f32x4 v = __builtin_nontemporal_load((const f32x4*)(x + (e - BATCH * CINCH)));
            r.x = f2bf(v[0]); r.y = f2bf(v[1]); r.z = f2bf(v[2]); r.w = f2bf(v[3]);
        }
        *(ushort4*)(xb + e) = r;
    } else {
        int i = (blockIdx.x - CAST_BLOCKS) * 256 + threadIdx.x;
        int o  = i >> 10;
        int r  = i & 1023;
        int k  = r >> 9;
        int ci = r & 511;
        wb[i] = f2bf(__builtin_nontemporal_load(W + o * 1024 + ci * 2 + k));
    }
}

// ---------------------------------------------------------------------------
// Kernel 2: GEMM + bias + activation -> bf16 gates z/f/o, each [T*B][H].
// Champion inner structure (R0/R6: 133 us healthy, R8/R9: 167 us on degraded-
// memory container; MFMA busy-time conserved at ~46 us in both). DO NOT
// RESTRUCTURE the K-loop (5 rounds of evidence). This round adds ONLY an
// XCD-chunked, N-fastest block swizzle: the 12 N-tiles sharing an A-panel run
// consecutively on the same XCD -> A-panel L2-hit, xb fetched from HBM ~once
// (ideal fetch ~37 MB vs measured 135 MB with x-fastest dispatch).
// ---------------------------------------------------------------------------
__device__ __forceinline__ void load_lds_16B(const ushort_t* g, ushort_t* l) {
    auto* gp = reinterpret_cast<const __attribute__((address_space(1))) unsigned int*>(
        reinterpret_cast<uintptr_t>(g));
    auto* lp = reinterpret_cast<__attribute__((address_space(3))) unsigned int*>(
        reinterpret_cast<uintptr_t>(l));
    __builtin_amdgcn_global_load_lds(gp, lp, 16, 0, 0);
}

__global__ __launch_bounds__(256) void gemm_gates_kernel(
    const ushort_t* __restrict__ xb, const ushort_t* __restrict__ wb,
    const float* __restrict__ bias,
    ushort_t* __restrict__ zb, ushort_t* __restrict__ fb, ushort_t* __restrict__ ob) {

    __shared__ ushort_t smem[2 * 128 * 64];   // As/Bs during K-loop; 128x128 out-tile in epilogue
    ushort_t* As = smem;
    ushort_t* Bs = smem + 128 * 64;

    const int tid  = threadIdx.x;
    const int w    = tid >> 6;
    const int lane = tid & 63;
    const int quad = lane >> 4;
    const int l15  = lane & 15;
    const int wm   = w & 1;
    const int wn   = w >> 1;

    // XCD-chunked bijective swizzle (3072 % 8 == 0), N-tile fastest in a chunk:
    // XCD k gets swz in [k*384,(k+1)*384) = 32 A-panels x 12 N-tiles each.
    const int bid = blockIdx.x;
    const int swz = (bid & 7) * 384 + (bid >> 3);
    const int mBase = (swz / 12) * 128;
    const int nBase = (swz % 12) * 128;

    const int srow = lane >> 3;
    const int scb  = lane & 7;

    f32x4 acc[4][4];
#pragma unroll
    for (int i = 0; i < 4; ++i)
#pragma unroll
        for (int j = 0; j < 4; ++j)
            acc[i][j] = (f32x4){0.f, 0.f, 0.f, 0.f};

    for (int kt = 0; kt < 16; ++kt) {
        __syncthreads();
        const long aOff = (kt < 8) ? (long)kt * 64 : (long)16 * 512 + (long)(kt - 8) * 64;
#pragma unroll
        for (int i = 0; i < 4; ++i) {
            const int row = w * 32 + i * 8 + srow;
            const int cbd = scb ^ (row & 7);
            const ushort_t* ga = xb + (long)(mBase + row) * 512 + aOff + cbd * 8;
            load_lds_16B(ga, &As[(w * 32 + i * 8) * 64]);
            const ushort_t* gb = wb + (long)(nBase + row) * 1024 + kt * 64 + cbd * 8;
            load_lds_16B(gb, &Bs[(w * 32 + i * 8) * 64]);
        }
        __syncthreads();

#pragma unroll
        for (int ks = 0; ks < 2; ++ks) {
            bf16x8 af[4], bfr[4];
            const int cbd = ks * 4 + quad;
#pragma unroll
            for (int mt = 0; mt < 4; ++mt) {
                int ml  = wm * 64 + mt * 16 + l15;
                int off = ml * 64 + ((cbd ^ (ml & 7)) * 8);
                af[mt] = __builtin_bit_cast(bf16x8, *(const u16x8*)(&As[off]));
            }
#pragma unroll
            for (int nt = 0; nt < 4; ++nt) {
                int nl  = wn * 64 + nt * 16 + l15;
                int off = nl * 64 + ((cbd ^ (nl & 7)) * 8);
                bfr[nt] = __builtin_bit_cast(bf16x8, *(const u16x8*)(&Bs[off]));
            }
#pragma unroll
            for (int mt = 0; mt < 4; ++mt)
#pragma unroll
                for (int nt = 0; nt < 4; ++nt)
                    acc[mt][nt] = __builtin_amdgcn_mfma_f32_16x16x32_bf16(
                        af[mt], bfr[nt], acc[mt][nt], 0, 0, 0);
        }
    }

    // ---- Epilogue: bias + activation into LDS (swizzled), then coalesced stores
    const int gate = nBase >> 9;            // block-uniform: 4 N-tiles per gate
    const int hb   = nBase & 511;

    __syncthreads();   // everyone done reading As/Bs
#pragma unroll
    for (int nt = 0; nt < 4; ++nt) {
        const int n_local = wn * 64 + nt * 16 + l15;
        const float bv = bias[nBase + n_local];
#pragma unroll
        for (int mt = 0; mt < 4; ++mt) {
#pragma unroll
            for (int r = 0; r < 4; ++r) {
                const int m_local = wm * 64 + mt * 16 + quad * 4 + r;
                float g = acc[mt][nt][r] + bv;
                float a;
                if (gate == 0) {
                    float e = __expf(-2.f * fabsf(g));
                    float t = (1.f - e) / (1.f + e);
                    a = copysignf(t, g);
                } else {
                    a = 1.f / (1.f + __expf(-g));
                }
                const int phys = ((n_local >> 3) ^ (m_local & 7)) * 8 + (n_local & 7);
                smem[m_local * 128 + phys] = f2bf(a);
            }
        }
    }
    __syncthreads();

    ushort_t* outp = (gate == 0) ? zb : (gate == 1) ? fb : ob;
#pragma unroll
    for (int s = 0; s < 8; ++s) {
        const int m_local = w * 32 + s * 4 + quad;
        const int blk = l15 ^ (m_local & 7);   // phys block holding logical block l15
        u16x8 v = *(const u16x8*)(&smem[m_local * 128 + blk * 8]);
        *(u16x8*)(outp + (long)(mBase + m_local) * 512 + hb + l15 * 8) = v;
    }
}

// ---------------------------------------------------------------------------
// Scan, chunked-parallel, TWO passes (prefix fused into apply):
//   compose: per-chunk (A,B) composition -> Acomp/Bcomp (2 MB, L2-resident)
//   apply:   local exclusive prefix over Acomp/Bcomp (<=31 L2-hit steps),
//            then apply+write. apply loads/stores nontemporal (last use).
// ---------------------------------------------------------------------------
__device__ __forceinline__ void scan_step(float z, float f, float& A, float& Bv) {
    Bv = f * Bv + (1.f - f) * z;
    A *= f;
}

__device__ __forceinline__ u16x4 ntload_u4(const ushort_t* p) {
    return __builtin_nontemporal_load((const u16x4*)p);
}

__global__ __launch_bounds__(256) void scan_compose(
    const ushort_t* __restrict__ zb, const ushort_t* __restrict__ fb,
    float* __restrict__ Acomp, float* __restrict__ Bcomp) {
    const int cg  = (blockIdx.x & 7) * 256 + threadIdx.x;   // 2048 col-groups/chunk
    const int ch  = blockIdx.x >> 3;
    const int col = cg * 4;
    const long base = (long)ch * CHL * NCOL + col;
    float Ax = 1.f, Ay = 1.f, Az = 1.f, Aw = 1.f;
    float Bx = 0.f, By = 0.f, Bz = 0.f, Bw = 0.f;
    const int U = 8;
    for (int w0 = 0; w0 < CHL; w0 += U) {
        u16x4 zr[U], fr[U];
#pragma unroll
        for (int u = 0; u < U; ++u) {
            const long idx = base + (long)(w0 + u) * NCOL;
            zr[u] = *(const u16x4*)(zb + idx);
            fr[u] = *(const u16x4*)(fb + idx);
        }
#pragma unroll
        for (int u = 0; u < U; ++u) {
            scan_step(bf2f(zr[u][0]), bf2f(fr[u][0]), Ax, Bx);
            scan_step(bf2f(zr[u][1]), bf2f(fr[u][1]), Ay, By);
            scan_step(bf2f(zr[u][2]), bf2f(fr[u][2]), Az, Bz);
            scan_step(bf2f(zr[u][3]), bf2f(fr[u][3]), Aw, Bw);
        }
    }
    *(f32x4*)(Acomp + (long)ch * NCOL + col) = (f32x4){Ax, Ay, Az, Aw};
    *(f32x4*)(Bcomp + (long)ch * NCOL + col) = (f32x4){Bx, By, Bz, Bw};
}

__global__ __launch_bounds__(256) void scan_apply(
    const ushort_t* __restrict__ zb, const ushort_t* __restrict__ fb,
    const ushort_t* __restrict__ ob,
    const float* __restrict__ Acomp, const float* __restrict__ Bcomp,
    float* __restrict__ out) {
    const int cg  = (blockIdx.x & 7) * 256 + threadIdx.x;
    const int ch  = blockIdx.x >> 3;
    const int col = cg * 4;
    const long base = (long)ch * CHL * NCOL + col;

    // local exclusive prefix over the chunk-compose results (L2-hit; 2 MB total)
    float cx = 0.f, cy = 0.f, cz = 0.f, cw = 0.f;
    for (int k = 0; k < ch; ++k) {
        f32x4 a4 = *(const f32x4*)(Acomp + (long)k * NCOL + col);
        f32x4 b4 = *(const f32x4*)(Bcomp + (long)k * NCOL + col);
        cx = a4[0] * cx + b4[0];
        cy = a4[1] * cy + b4[1];
        cz = a4[2] * cz + b4[2];
        cw = a4[3] * cw + b4[3];
    }

    float hx = 0.f, hy = 0.f, hz = 0.f, hw = 0.f;
    const int U = 8;
    for (int w0 = 0; w0 < CHL; w0 += U) {
        u16x4 zr[U], fr[U], orr[U];
#pragma unroll
        for (int u = 0; u < U; ++u) {
            const long idx = base + (long)(w0 + u) * NCOL;
            zr[u]  = ntload_u4(zb + idx);
            fr[u]  = ntload_u4(fb + idx);
            orr[u] = ntload_u4(ob + idx);
        }
#pragma unroll
        for (int u = 0; u < U; ++u) {
            float f, z;
            f = bf2f(fr[u][0]); z = bf2f(zr[u][0]); cx = f * cx + (1.f - f) * z; hx = cx * bf2f(orr[u][0]);
            f = bf2f(fr[u][1]); z = bf2f(zr[u][1]); cy = f * cy + (1.f - f) * z; hy = cy * bf2f(orr[u][1]);
            f = bf2f(fr[u][2]); z = bf2f(zr[u][2]); cz = f * cz + (1.f - f) * z; hz = cz * bf2f(orr[u][2]);
            f = bf2f(fr[u][3]); z = bf2f(zr[u][3]); cw = f * cw + (1.f - f) * z; hw = cw * bf2f(orr[u][3]);
            f32x4 hv = (f32x4){hx, hy, hz, hw};
            __builtin_nontemporal_store(hv, (f32x4*)(out + base + (long)(w0 + u) * NCOL));
        }
    }
    if (ch == NCH - 1) {
        *(f32x4*)(out + (long)SEQ * NCOL + col)        = (f32x4){hx, hy, hz, hw};  // h_last
        *(f32x4*)(out + (long)SEQ * NCOL + NCOL + col) = (f32x4){cx, cy, cz, cw};  // c_last
    }
}

// ---------------------------------------------------------------------------
extern "C" void kernel_launch(void* const* d_in, const int* in_sizes, int n_in,
                              void* d_out, int out_size, void* d_ws, size_t ws_size,
                              hipStream_t stream) {
    const float* x  = (const float*)d_in[0];   // (T, B, Cin)
    const float* W  = (const float*)d_in[1];   // (3H, Cin, 2)
    const float* bi = (const float*)d_in[2];   // (3H,)
    float* out = (float*)d_out;

    char* ws = (char*)d_ws;
    const size_t xbN = (size_t)(TBM + BATCH) * CINCH;   // padded bf16 x
    const size_t wbN = (size_t)NDIM * KRED;
    const size_t gN  = (size_t)TBM * HDIM;
    ushort_t* xb = (ushort_t*)ws;
    ushort_t* wb = (ushort_t*)(ws + xbN * 2);
    ushort_t* zb = (ushort_t*)(ws + xbN * 2 + wbN * 2);
    ushort_t* fb = zb + gN;
    ushort_t* ob = fb + gN;
    // scan scratch reuses the xb region (dead after the GEMM): 2 MB << 33.5 MB
    float* Acomp = (float*)ws;
    float* Bcomp = Acomp + NCH * NCOL;

    prep_kernel<<<CAST_BLOCKS + 6144, 256, 0, stream>>>(x, xb, W, wb);
    gemm_gates_kernel<<<3072, 256, 0, stream>>>(xb, wb, bi, zb, fb, ob);
    scan_compose<<<NCH * 8, 256, 0, stream>>>(zb, fb, Acomp, Bcomp);
    scan_apply<<<NCH * 8, 256, 0, stream>>>(zb, fb, ob, Acomp, Bcomp, out);
}